// Round 3
// baseline (293.583 us; speedup 1.0000x reference)
//
#include <hip/hip_runtime.h>

#define INCH 128
#define C1   16
#define C2   64
#define LOCB 7                   // log2(nodes per bucket)
#define BNODES (1 << LOCB)       // 128 nodes per bucket
#define CAP  8192                // padded edge capacity per bucket
#define ROWBITS 17
#define ROWMASK ((1 << ROWBITS) - 1)
#define SENT 0xFFFFFFFFu         // sentinel: src field = 0x1FFFF >= n -> filtered
#define STAGE_CAP 8448           // per-block staged edges (slice <= 8211)

typedef int iv4 __attribute__((ext_vector_type(4)));
typedef unsigned short usv8 __attribute__((ext_vector_type(8)));

// bf16 helpers: RTNE store, shift load
__device__ __forceinline__ unsigned short f2bf(float f) {
    unsigned u = __float_as_uint(f);
    return (unsigned short)((u + 0x7FFF + ((u >> 16) & 1)) >> 16);
}
__device__ __forceinline__ float bf2f(unsigned short s) {
    return __uint_as_float((unsigned)s << 16);
}

// ---------------- binit: gcur[b] = b*CAP -----------------------------------
__global__ void binit_kernel(int* __restrict__ gcur, int K) {
    int t = blockIdx.x * blockDim.x + threadIdx.x;
    if (t < K) gcur[t] = t * CAP;
}

// ---------------- bucket edges via block-local staging sort ----------------
// Per block: LDS histogram of slice -> scan -> global 16-aligned reservation
// -> scatter slice into LDS stage grouped by bucket -> coalesced run write
// with sentinel pad. Every reserved 64B line is written once, contiguously.
__global__ __launch_bounds__(256) void bucket_kernel(
    const int* __restrict__ row, const int* __restrict__ col,
    int* __restrict__ gcur, int* __restrict__ barr,
    int e, int n, int K, int nblocks)
{
    __shared__ int cnt[1024];       // per-bucket count for this slice
    __shared__ int part[256];       // scan partials
    __shared__ int ofs[1024];       // staging offset (exclusive scan)
    __shared__ int lcur[1024];      // staging cursor
    __shared__ int gst[1024];       // reserved global start per bucket
    __shared__ int stage[STAGE_CAP];// packed edges grouped by bucket (~33KB)
    int tid = threadIdx.x;
    int e4 = e >> 2;
    long b0 = (long)blockIdx.x * e4 / nblocks;
    long b1 = (long)(blockIdx.x + 1) * e4 / nblocks;
    const iv4* c4p = (const iv4*)col;
    const iv4* r4p = (const iv4*)row;

    for (int i = tid; i < 1024; i += 256) cnt[i] = 0;
    __syncthreads();

    // ---- pass A: histogram of this slice
    for (long i = b0 + tid; i < b1; i += 256) {
        iv4 c4 = c4p[i], r4 = r4p[i];
        #pragma unroll
        for (int k = 0; k < 4; ++k) {
            unsigned c = (unsigned)c4[k], r = (unsigned)r4[k];
            if (c < (unsigned)n && r < (unsigned)n)
                atomicAdd(&cnt[c >> LOCB], 1);
        }
    }
    if (blockIdx.x == 0) {                       // global tail (e % 4)
        for (int i = e4 * 4 + tid; i < e; i += 256) {
            unsigned c = (unsigned)col[i], r = (unsigned)row[i];
            if (c < (unsigned)n && r < (unsigned)n)
                atomicAdd(&cnt[c >> LOCB], 1);
        }
    }
    __syncthreads();

    // ---- scan: 4 buckets/thread serial + Hillis-Steele over 256 partials
    int c0 = cnt[4 * tid], c1 = cnt[4 * tid + 1];
    int c2 = cnt[4 * tid + 2], c3 = cnt[4 * tid + 3];
    int tot = c0 + c1 + c2 + c3;
    part[tid] = tot;
    __syncthreads();
    for (int off = 1; off < 256; off <<= 1) {
        int v = (tid >= off) ? part[tid - off] : 0;
        __syncthreads();
        part[tid] += v;
        __syncthreads();
    }
    {
        int base = part[tid] - tot;              // exclusive
        ofs[4 * tid]     = base;
        ofs[4 * tid + 1] = base + c0;
        ofs[4 * tid + 2] = base + c0 + c1;
        ofs[4 * tid + 3] = base + c0 + c1 + c2;
        lcur[4 * tid]     = base;
        lcur[4 * tid + 1] = base + c0;
        lcur[4 * tid + 2] = base + c0 + c1;
        lcur[4 * tid + 3] = base + c0 + c1 + c2;
    }
    // ---- reserve global space (16-edge aligned -> 64B lines exclusive)
    for (int b = tid; b < K; b += 256) {
        int c = cnt[b];
        gst[b] = c ? atomicAdd(&gcur[b], (c + 15) & ~15) : 0;
    }
    __syncthreads();

    // ---- pass B: re-read slice (L2-hot), scatter into LDS stage
    for (long i = b0 + tid; i < b1; i += 256) {
        iv4 c4 = c4p[i], r4 = r4p[i];
        #pragma unroll
        for (int k = 0; k < 4; ++k) {
            unsigned c = (unsigned)c4[k], r = (unsigned)r4[k];
            if (c < (unsigned)n && r < (unsigned)n) {
                int b = c >> LOCB;
                int pos = atomicAdd(&lcur[b], 1);        // LDS int atomic
                if ((unsigned)pos < (unsigned)STAGE_CAP)
                    stage[pos] = (int)(r | ((c & (BNODES - 1)) << ROWBITS));
            }
        }
    }
    if (blockIdx.x == 0) {
        for (int i = e4 * 4 + tid; i < e; i += 256) {
            unsigned c = (unsigned)col[i], r = (unsigned)row[i];
            if (c < (unsigned)n && r < (unsigned)n) {
                int b = c >> LOCB;
                int pos = atomicAdd(&lcur[b], 1);
                if ((unsigned)pos < (unsigned)STAGE_CAP)
                    stage[pos] = (int)(r | ((c & (BNODES - 1)) << ROWBITS));
            }
        }
    }
    __syncthreads();

    // ---- write-out: per-bucket runs, coalesced lanes, sentinel pad to 16
    int wid = tid >> 6, lane = tid & 63;
    for (int b = wid; b < K; b += 4) {
        int c = cnt[b];
        if (!c) continue;
        int g = gst[b], o = ofs[b];
        int p = (c + 15) & ~15;
        int lim = (b + 1) * CAP;
        for (int j = lane; j < p; j += 64) {
            int v = (j < c) ? stage[o + j] : (int)SENT;
            if (g + j < lim) barr[g + j] = v;
        }
    }
}

// ---------------- exclusive scan of padded bucket lengths -> bbase ---------
__global__ __launch_bounds__(1024) void bucket_scan_kernel(
    const int* __restrict__ gcur, int* __restrict__ bbase, int K)
{
    __shared__ int tmp[1024];
    int t = threadIdx.x;
    int len = 0;
    if (t < K) {
        int l = gcur[t] - t * CAP;
        len = (l < 0) ? 0 : (l > CAP ? CAP : l);
    }
    tmp[t] = len;
    __syncthreads();
    for (int off = 1; off < 1024; off <<= 1) {
        int v = (t >= off) ? tmp[t - off] : 0;
        __syncthreads();
        tmp[t] += v;
        __syncthreads();
    }
    if (t < K) bbase[t] = tmp[t] - len;   // exclusive
}

// ---------------- per-bucket counting sort -> global CSR -------------------
__global__ __launch_bounds__(256) void sort_kernel(
    const int* __restrict__ barr, const int* __restrict__ gcur,
    const int* __restrict__ bbase,
    int* __restrict__ cnt, int* __restrict__ offs, float* __restrict__ inv,
    int* __restrict__ sorted, int n)
{
    __shared__ int lcnt[BNODES];
    __shared__ int lcur[BNODES];
    __shared__ int tmp[BNODES];
    int b = blockIdx.x;
    int tid = threadIdx.x;
    if (tid < BNODES) lcnt[tid] = 0;
    __syncthreads();
    int base = b * CAP;
    int len = gcur[b] - base;
    if (len < 0) len = 0;
    if (len > CAP) len = CAP;
    int len4 = len >> 2;
    const iv4* b4 = (const iv4*)(barr + base);
    for (int i = tid; i < len4; i += 256) {
        iv4 p4 = b4[i];
        #pragma unroll
        for (int k = 0; k < 4; ++k) {
            unsigned pk = (unsigned)p4[k];
            if ((pk & ROWMASK) < (unsigned)n)
                atomicAdd(&lcnt[(pk >> ROWBITS) & (BNODES - 1)], 1);
        }
    }
    for (int i = len4 * 4 + tid; i < len; i += 256) {       // safety tail
        unsigned pk = (unsigned)barr[base + i];
        if ((pk & ROWMASK) < (unsigned)n)
            atomicAdd(&lcnt[(pk >> ROWBITS) & (BNODES - 1)], 1);
    }
    __syncthreads();
    int v = (tid < BNODES) ? lcnt[tid] : 0;
    if (tid < BNODES) tmp[tid] = v;
    __syncthreads();
    for (int off = 1; off < BNODES; off <<= 1) {
        int t2 = (tid < BNODES && tid >= off) ? tmp[tid - off] : 0;
        __syncthreads();
        if (tid < BNODES) tmp[tid] += t2;
        __syncthreads();
    }
    int gbase = bbase[b];
    if (tid < BNODES) {
        int exc = tmp[tid] - v;
        lcur[tid] = exc;
        int node = (b << LOCB) + tid;
        if (node < n) {
            cnt[node]  = v;
            offs[node] = gbase + exc;
            inv[node]  = rsqrtf((float)(v + 1));
        }
    }
    __syncthreads();
    for (int i = tid; i < len4; i += 256) {
        iv4 p4 = b4[i];
        #pragma unroll
        for (int k = 0; k < 4; ++k) {
            unsigned pk = (unsigned)p4[k];
            if ((pk & ROWMASK) < (unsigned)n) {
                int loc = (pk >> ROWBITS) & (BNODES - 1);
                int pos = atomicAdd(&lcur[loc], 1);          // LDS int atomic
                if ((unsigned)pos < (unsigned)CAP)
                    sorted[gbase + pos] = (int)(pk & ROWMASK);
            }
        }
    }
    for (int i = len4 * 4 + tid; i < len; i += 256) {
        unsigned pk = (unsigned)barr[base + i];
        if ((pk & ROWMASK) < (unsigned)n) {
            int loc = (pk >> ROWBITS) & (BNODES - 1);
            int pos = atomicAdd(&lcur[loc], 1);
            if ((unsigned)pos < (unsigned)CAP)
                sorted[gbase + pos] = (int)(pk & ROWMASK);
        }
    }
}

// ---------------- linear1: xW1s_bf = bf16((x@W1)*inv), xT1 = x@t1_W + t1_b -
__global__ __launch_bounds__(256) void linear1_kernel(
    const float* __restrict__ x, const float* __restrict__ W1,
    const float* __restrict__ T1, const float* __restrict__ t1b,
    const float* __restrict__ inv,
    unsigned short* __restrict__ xW1s_bf, float* __restrict__ xT1, int n)
{
    __shared__ float Wc[INCH][32];        // [:,0:16]=W1, [:,16:32]=t1_W
    __shared__ float xs[16][INCH + 4];
    int tid = threadIdx.x;

    for (int i = tid; i < INCH * C1; i += 256) {
        int k = i / C1, c = i % C1;
        Wc[k][c]      = W1[i];
        Wc[k][c + 16] = T1[i];
    }
    int node0 = blockIdx.x * 16;
    for (int i = tid; i < 16 * (INCH / 4); i += 256) {
        int r = i / (INCH / 4);
        int cc = i % (INCH / 4);
        int node = node0 + r;
        float4 v = make_float4(0.f, 0.f, 0.f, 0.f);
        if (node < n) v = ((const float4*)x)[(size_t)node * (INCH / 4) + cc];
        ((float4*)&xs[r][0])[cc] = v;
    }
    __syncthreads();

    int ch = tid & 15, nl = tid >> 4;
    int node = node0 + nl;
    if (node >= n) return;
    float a1 = 0.f, a2 = 0.f;
    #pragma unroll
    for (int k = 0; k < INCH; ++k) {
        float xv = xs[nl][k];
        a1 += xv * Wc[k][ch];
        a2 += xv * Wc[k][ch + 16];
    }
    xW1s_bf[(node << 4) + ch] = f2bf(a1 * inv[node]);  // pre-scaled by inv[src]
    xT1[(node << 4) + ch]     = a2 + t1b[ch];
}

// ---- gather core: 4 lanes/node (2 edge-parities x 2 channel-halves),
//      ushort8 (16B) gathers, register accumulation, shfl_xor(2) combine.
#define GATHER_ACC(SRCBUF)                                                    \
    float a0 = 0.f, a1 = 0.f, a2 = 0.f, a3 = 0.f,                             \
          a4 = 0.f, a5 = 0.f, a6 = 0.f, a7 = 0.f;                             \
    {                                                                         \
        int p = beg + pr;                                                     \
        for (; p + 6 < end; p += 8) {                                         \
            int s0 = sorted[p],     s1 = sorted[p + 2];                       \
            int s2 = sorted[p + 4], s3 = sorted[p + 6];                       \
            usv8 v0 = *(const usv8*)(SRCBUF + ((size_t)s0 << 4) + chb);       \
            usv8 v1 = *(const usv8*)(SRCBUF + ((size_t)s1 << 4) + chb);       \
            usv8 v2 = *(const usv8*)(SRCBUF + ((size_t)s2 << 4) + chb);       \
            usv8 v3 = *(const usv8*)(SRCBUF + ((size_t)s3 << 4) + chb);       \
            a0 += bf2f(v0[0]) + bf2f(v1[0]) + bf2f(v2[0]) + bf2f(v3[0]);      \
            a1 += bf2f(v0[1]) + bf2f(v1[1]) + bf2f(v2[1]) + bf2f(v3[1]);      \
            a2 += bf2f(v0[2]) + bf2f(v1[2]) + bf2f(v2[2]) + bf2f(v3[2]);      \
            a3 += bf2f(v0[3]) + bf2f(v1[3]) + bf2f(v2[3]) + bf2f(v3[3]);      \
            a4 += bf2f(v0[4]) + bf2f(v1[4]) + bf2f(v2[4]) + bf2f(v3[4]);      \
            a5 += bf2f(v0[5]) + bf2f(v1[5]) + bf2f(v2[5]) + bf2f(v3[5]);      \
            a6 += bf2f(v0[6]) + bf2f(v1[6]) + bf2f(v2[6]) + bf2f(v3[6]);      \
            a7 += bf2f(v0[7]) + bf2f(v1[7]) + bf2f(v2[7]) + bf2f(v3[7]);      \
        }                                                                     \
        for (; p < end; p += 2) {                                             \
            int s0 = sorted[p];                                               \
            usv8 v0 = *(const usv8*)(SRCBUF + ((size_t)s0 << 4) + chb);       \
            a0 += bf2f(v0[0]); a1 += bf2f(v0[1]);                             \
            a2 += bf2f(v0[2]); a3 += bf2f(v0[3]);                             \
            a4 += bf2f(v0[4]); a5 += bf2f(v0[5]);                             \
            a6 += bf2f(v0[6]); a7 += bf2f(v0[7]);                             \
        }                                                                     \
    }                                                                         \
    a0 += __shfl_xor(a0, 2); a1 += __shfl_xor(a1, 2);                         \
    a2 += __shfl_xor(a2, 2); a3 += __shfl_xor(a3, 2);                         \
    a4 += __shfl_xor(a4, 2); a5 += __shfl_xor(a5, 2);                         \
    a6 += __shfl_xor(a6, 2); a7 += __shfl_xor(a7, 2);

// ---------------- agg1 CSR v2: register gather + fused epilogue1 -----------
// 64 nodes/block, 256 threads: node = blk*64 + tid/4; lane quad = {parity, chb}
__global__ __launch_bounds__(256) void agg1_csr_kernel(
    const int* __restrict__ sorted, const int* __restrict__ offs,
    const int* __restrict__ cnt, const float* __restrict__ inv,
    const unsigned short* __restrict__ xW1s_bf, const float* __restrict__ xT1,
    const float* __restrict__ b1,
    float* __restrict__ h, unsigned short* __restrict__ hs_bf, int n)
{
    int tid = threadIdx.x;
    int node = blockIdx.x * 64 + (tid >> 2);
    int pr  = (tid >> 1) & 1;        // edge parity
    int chb = (tid & 1) << 3;        // channel half: 0..7 / 8..15
    int beg = 0, end = 0;
    if (node < n) { beg = offs[node]; end = beg + cnt[node]; }

    GATHER_ACC(xW1s_bf)

    if (node >= n || pr != 0) return;     // quad-uniform wrt shfl partners
    size_t idx = ((size_t)node << 4) + chb;
    usv8 selfv = *(const usv8*)(xW1s_bf + idx);
    float ic = inv[node];
    float hv0 = fmaxf((a0 + bf2f(selfv[0])) * ic + b1[chb + 0], 0.f) + xT1[idx + 0];
    float hv1 = fmaxf((a1 + bf2f(selfv[1])) * ic + b1[chb + 1], 0.f) + xT1[idx + 1];
    float hv2 = fmaxf((a2 + bf2f(selfv[2])) * ic + b1[chb + 2], 0.f) + xT1[idx + 2];
    float hv3 = fmaxf((a3 + bf2f(selfv[3])) * ic + b1[chb + 3], 0.f) + xT1[idx + 3];
    float hv4 = fmaxf((a4 + bf2f(selfv[4])) * ic + b1[chb + 4], 0.f) + xT1[idx + 4];
    float hv5 = fmaxf((a5 + bf2f(selfv[5])) * ic + b1[chb + 5], 0.f) + xT1[idx + 5];
    float hv6 = fmaxf((a6 + bf2f(selfv[6])) * ic + b1[chb + 6], 0.f) + xT1[idx + 6];
    float hv7 = fmaxf((a7 + bf2f(selfv[7])) * ic + b1[chb + 7], 0.f) + xT1[idx + 7];
    ((float4*)(h + idx))[0] = make_float4(hv0, hv1, hv2, hv3);
    ((float4*)(h + idx))[1] = make_float4(hv4, hv5, hv6, hv7);
    usv8 hb;
    hb[0] = f2bf(hv0 * ic); hb[1] = f2bf(hv1 * ic);
    hb[2] = f2bf(hv2 * ic); hb[3] = f2bf(hv3 * ic);
    hb[4] = f2bf(hv4 * ic); hb[5] = f2bf(hv5 * ic);
    hb[6] = f2bf(hv6 * ic); hb[7] = f2bf(hv7 * ic);
    *(usv8*)(hs_bf + idx) = hb;
}

// ---------------- agg2 v2: register gather + fused 16->64 linears ----------
// 64 nodes/block. Gather into regs, plain LDS stores (exclusive), matmul epi.
__global__ __launch_bounds__(256) void agg2_fused_kernel(
    const int* __restrict__ sorted, const int* __restrict__ offs,
    const int* __restrict__ cnt, const float* __restrict__ inv,
    const unsigned short* __restrict__ hs_bf, const float* __restrict__ h,
    const float* __restrict__ W2, const float* __restrict__ T2,
    const float* __restrict__ b2, const float* __restrict__ t2b,
    float* __restrict__ out, int n)
{
    __shared__ float Wc[C1][128];     // [:,0:64]=W2, [:,64:128]=t2_W (8 KB)
    __shared__ float acc_s[64][C1];   // aggregated (incl. self, *ic)   (4 KB)
    __shared__ float h_s[64][C1];     // unscaled h for identity2       (4 KB)
    int tid = threadIdx.x;

    for (int i = tid; i < C1 * 128; i += 256) {
        int k = i >> 7, c = i & 127;
        Wc[k][c] = (c < 64) ? W2[k * C2 + c] : T2[k * C2 + (c - 64)];
    }
    {   // stage h rows (contiguous across the block -> coalesced float4)
        int node0 = blockIdx.x * 64;
        if (tid < 256) {
            float4 v = make_float4(0.f, 0.f, 0.f, 0.f);
            if (node0 + (tid >> 2) < n)
                v = ((const float4*)h)[(size_t)node0 * 4 + tid];
            ((float4*)&h_s[0][0])[tid] = v;
        }
    }

    int node = blockIdx.x * 64 + (tid >> 2);
    int pr  = (tid >> 1) & 1;
    int chb = (tid & 1) << 3;
    int beg = 0, end = 0;
    if (node < n) { beg = offs[node]; end = beg + cnt[node]; }

    GATHER_ACC(hs_bf)

    if (node < n && pr == 0) {
        size_t idx = ((size_t)node << 4) + chb;
        usv8 selfv = *(const usv8*)(hs_bf + idx);
        float ic = inv[node];
        int loc = tid >> 2;
        float4* ap = (float4*)&acc_s[loc][chb];
        ap[0] = make_float4((a0 + bf2f(selfv[0])) * ic, (a1 + bf2f(selfv[1])) * ic,
                            (a2 + bf2f(selfv[2])) * ic, (a3 + bf2f(selfv[3])) * ic);
        ap[1] = make_float4((a4 + bf2f(selfv[4])) * ic, (a5 + bf2f(selfv[5])) * ic,
                            (a6 + bf2f(selfv[6])) * ic, (a7 + bf2f(selfv[7])) * ic);
    }
    __syncthreads();

    // 16->64 matmuls: weights hoisted to registers, acc/h_s broadcast reads
    int och = tid & 63, g = tid >> 6;        // wave g handles locs [16g, 16g+16)
    float w1r[C1], w2r[C1];
    #pragma unroll
    for (int k = 0; k < C1; ++k) { w1r[k] = Wc[k][och]; w2r[k] = Wc[k][och + 64]; }
    float bb = b2[och], tb = t2b[och];
    for (int q = 0; q < 16; ++q) {
        int loc = (g << 4) + q;
        int node2 = blockIdx.x * 64 + loc;
        if (node2 >= n) continue;
        float s1 = bb, s2 = tb;
        #pragma unroll
        for (int k = 0; k < C1; ++k) {
            s1 += acc_s[loc][k] * w1r[k];
            s2 += h_s[loc][k]   * w2r[k];
        }
        out[(size_t)node2 * C2 + och] = fmaxf(s1, 0.f) + s2;
    }
}

extern "C" void kernel_launch(void* const* d_in, const int* in_sizes, int n_in,
                              void* d_out, int out_size, void* d_ws, size_t ws_size,
                              hipStream_t stream) {
    const float* x   = (const float*)d_in[0];
    const int*   ei  = (const int*)d_in[1];
    const float* W1  = (const float*)d_in[2];
    const float* b1  = (const float*)d_in[3];
    const float* W2  = (const float*)d_in[4];
    const float* b2  = (const float*)d_in[5];
    const float* T1  = (const float*)d_in[6];
    const float* t1b = (const float*)d_in[7];
    const float* T2  = (const float*)d_in[8];
    const float* t2b = (const float*)d_in[9];
    float* out = (float*)d_out;

    const int n = in_sizes[0] / INCH;       // 100000
    const int e = in_sizes[1] / 2;          // 3200000
    const int* row = ei;
    const int* col = ei + e;
    const int K = (n + BNODES - 1) >> LOCB; // 782 buckets

    // workspace layout — data-indexed buffers (sorted, barr) last
    char* ws = (char*)d_ws;
    int*   gcur  = (int*)ws;                          ws += 4096;
    int*   bbase = (int*)ws;                          ws += 4096;
    int*   cnt   = (int*)ws;                          ws += (size_t)n * 4;
    int*   offs  = (int*)ws;                          ws += (size_t)n * 4;
    float* inv   = (float*)ws;                        ws += (size_t)n * 4;
    float* xT1   = (float*)ws;                        ws += (size_t)n * C1 * 4;
    float* h     = (float*)ws;                        ws += (size_t)n * C1 * 4;
    unsigned short* xW1s_bf = (unsigned short*)ws;    ws += (size_t)n * C1 * 2;  // 3.2 MB
    unsigned short* hs_bf   = (unsigned short*)ws;    ws += (size_t)n * C1 * 2;  // 3.2 MB
    int*   sorted= (int*)ws;                          ws += (size_t)K * CAP * 4; // 25.6 MB
    int*   barr  = (int*)ws;                          ws += (size_t)K * CAP * 4; // 25.6 MB

    const int B = 256;
    const int nbb = 390;     // bucket_kernel blocks (slice ~8205 edges < STAGE_CAP)

    binit_kernel      <<<(K + B - 1) / B, B, 0, stream>>>(gcur, K);
    bucket_kernel     <<<nbb, B, 0, stream>>>(row, col, gcur, barr, e, n, K, nbb);
    bucket_scan_kernel<<<1, 1024, 0, stream>>>(gcur, bbase, K);
    sort_kernel       <<<K, B, 0, stream>>>(barr, gcur, bbase, cnt, offs, inv, sorted, n);

    linear1_kernel <<<(n + 15) / 16, B, 0, stream>>>(x, W1, T1, t1b, inv, xW1s_bf, xT1, n);
    agg1_csr_kernel<<<(n + 63) / 64, B, 0, stream>>>(sorted, offs, cnt, inv, xW1s_bf, xT1, b1, h, hs_bf, n);

    agg2_fused_kernel<<<(n + 63) / 64, B, 0, stream>>>(sorted, offs, cnt, inv, hs_bf, h,
                                                       W2, T2, b2, t2b, out, n);
}

// Round 4
// 272.899 us; speedup vs baseline: 1.0758x; 1.0758x over previous
//
#include <hip/hip_runtime.h>

#define INCH 128
#define C1   16
#define C2   64
#define LOCB 7                   // log2(nodes per bucket)
#define BNODES (1 << LOCB)       // 128 nodes per bucket
#define CAP  8192                // padded edge capacity per bucket
#define ROWBITS 17
#define ROWMASK ((1 << ROWBITS) - 1)
#define SENT 0xFFFFFFFFu         // sentinel: src field = 0x1FFFF >= n -> filtered
#define BSLACK 384               // per-bucket slack in sorted[] for 4-padding (3*BNODES)

typedef int iv4 __attribute__((ext_vector_type(4)));
typedef unsigned short usv8 __attribute__((ext_vector_type(8)));

// bf16 helpers: RTNE store, shift load
__device__ __forceinline__ unsigned short f2bf(float f) {
    unsigned u = __float_as_uint(f);
    return (unsigned short)((u + 0x7FFF + ((u >> 16) & 1)) >> 16);
}
__device__ __forceinline__ float bf2f(unsigned short s) {
    return __uint_as_float((unsigned)s << 16);
}

// ---------------- binit: gcur[b] = b*CAP; zero pad-source rows -------------
__global__ void binit_kernel(int* __restrict__ gcur, int K,
                             int* __restrict__ xz, int* __restrict__ hz) {
    int t = blockIdx.x * blockDim.x + threadIdx.x;
    if (t < K) gcur[t] = t * CAP;
    if (blockIdx.x == 0 && threadIdx.x < 8) {   // row n of xW1s_bf / hs_bf = 0
        xz[threadIdx.x] = 0;
        hz[threadIdx.x] = 0;
    }
}

// ---------------- bucket edges, line-aligned padded reservations -----------
// (round-2 version: direct global scatter; write amplification accepted —
//  the staged variant traded it for a serial write-out loop and lost 17us)
__global__ __launch_bounds__(256) void bucket_kernel(
    const int* __restrict__ row, const int* __restrict__ col,
    int* __restrict__ gcur, int* __restrict__ barr,
    int e, int n, int K, int nblocks)
{
    __shared__ int cnt[1024];     // valid count per bucket
    __shared__ int cur[1024];     // write cursor
    __shared__ int sst[1024];     // chunk start
    int e4 = e >> 2;
    long b0 = (long)blockIdx.x * e4 / nblocks;
    long b1 = (long)(blockIdx.x + 1) * e4 / nblocks;
    const iv4* c4p = (const iv4*)col;
    const iv4* r4p = (const iv4*)row;
    for (int i = threadIdx.x; i < 1024; i += 256) cnt[i] = 0;
    __syncthreads();
    for (long i = b0 + threadIdx.x; i < b1; i += 256) {
        iv4 c4 = c4p[i], r4 = r4p[i];
        #pragma unroll
        for (int k = 0; k < 4; ++k) {
            unsigned c = (unsigned)c4[k], r = (unsigned)r4[k];
            if (c < (unsigned)n && r < (unsigned)n)
                atomicAdd(&cnt[c >> LOCB], 1);
        }
    }
    if (blockIdx.x == 0) {
        for (int i = e4 * 4 + threadIdx.x; i < e; i += 256) {
            unsigned c = (unsigned)col[i], r = (unsigned)row[i];
            if (c < (unsigned)n && r < (unsigned)n)
                atomicAdd(&cnt[c >> LOCB], 1);
        }
    }
    __syncthreads();
    for (int i = threadIdx.x; i < K; i += 256) {
        int c = cnt[i];
        int start = c ? atomicAdd(&gcur[i], (c + 15) & ~15) : 0;
        cur[i] = start;
        sst[i] = start;
    }
    __syncthreads();
    for (long i = b0 + threadIdx.x; i < b1; i += 256) {
        iv4 c4 = c4p[i], r4 = r4p[i];
        #pragma unroll
        for (int k = 0; k < 4; ++k) {
            unsigned c = (unsigned)c4[k], r = (unsigned)r4[k];
            if (c < (unsigned)n && r < (unsigned)n) {
                int b = c >> LOCB;
                int slot = atomicAdd(&cur[b], 1);          // LDS int atomic
                if ((unsigned)slot < (unsigned)((b + 1) * CAP))
                    barr[slot] = (int)(r | ((c & (BNODES - 1)) << ROWBITS));
            }
        }
    }
    if (blockIdx.x == 0) {
        for (int i = e4 * 4 + threadIdx.x; i < e; i += 256) {
            unsigned c = (unsigned)col[i], r = (unsigned)row[i];
            if (c < (unsigned)n && r < (unsigned)n) {
                int b = c >> LOCB;
                int slot = atomicAdd(&cur[b], 1);
                if ((unsigned)slot < (unsigned)((b + 1) * CAP))
                    barr[slot] = (int)(r | ((c & (BNODES - 1)) << ROWBITS));
            }
        }
    }
    __syncthreads();
    // sentinel-fill the pad so every reserved line is fully written
    for (int i = threadIdx.x; i < K; i += 256) {
        int c = cnt[i];
        if (!c) continue;
        int start = sst[i];
        int end = start + c;
        int re  = start + ((c + 15) & ~15);
        int lim = (i + 1) * CAP;
        if (end > lim) end = lim;
        if (re  > lim) re  = lim;
        for (int j = end; j < re; ++j) barr[j] = (int)SENT;
    }
}

// ---------------- exclusive scan of bucket lengths (+slack) -> bbase -------
__global__ __launch_bounds__(1024) void bucket_scan_kernel(
    const int* __restrict__ gcur, int* __restrict__ bbase, int K)
{
    __shared__ int tmp[1024];
    int t = threadIdx.x;
    int len = 0;
    if (t < K) {
        int l = gcur[t] - t * CAP;
        len = (l < 0) ? 0 : (l > CAP ? CAP : l);
        len += BSLACK;            // room for per-node 4-padding in sorted[]
    }
    tmp[t] = len;
    __syncthreads();
    for (int off = 1; off < 1024; off <<= 1) {
        int v = (t >= off) ? tmp[t - off] : 0;
        __syncthreads();
        tmp[t] += v;
        __syncthreads();
    }
    if (t < K) bbase[t] = tmp[t] - len;   // exclusive
}

// ---------------- per-bucket counting sort -> global CSR (4-padded) --------
// Per-node segments padded to multiples of 4 edges; pad slots hold index n
// (a zeroed source row), so agg loops need no tail handling and index loads
// can be 16B-aligned dwordx4.
__global__ __launch_bounds__(256) void sort_kernel(
    const int* __restrict__ barr, const int* __restrict__ gcur,
    const int* __restrict__ bbase,
    int* __restrict__ cnt, int* __restrict__ offs, float* __restrict__ inv,
    int* __restrict__ sorted, int n)
{
    __shared__ int lcnt[BNODES];
    __shared__ int lcur[BNODES];
    __shared__ int tmp[BNODES];
    int b = blockIdx.x;
    int tid = threadIdx.x;
    if (tid < BNODES) lcnt[tid] = 0;
    __syncthreads();
    int base = b * CAP;
    int len = gcur[b] - base;
    if (len < 0) len = 0;
    if (len > CAP) len = CAP;
    int len4 = len >> 2;
    const iv4* b4 = (const iv4*)(barr + base);
    for (int i = tid; i < len4; i += 256) {
        iv4 p4 = b4[i];
        #pragma unroll
        for (int k = 0; k < 4; ++k) {
            unsigned pk = (unsigned)p4[k];
            if ((pk & ROWMASK) < (unsigned)n)
                atomicAdd(&lcnt[(pk >> ROWBITS) & (BNODES - 1)], 1);
        }
    }
    for (int i = len4 * 4 + tid; i < len; i += 256) {       // safety tail
        unsigned pk = (unsigned)barr[base + i];
        if ((pk & ROWMASK) < (unsigned)n)
            atomicAdd(&lcnt[(pk >> ROWBITS) & (BNODES - 1)], 1);
    }
    __syncthreads();
    int v  = (tid < BNODES) ? lcnt[tid] : 0;
    int pc = (v + 3) & ~3;                 // 4-padded per-node count
    if (tid < BNODES) tmp[tid] = pc;
    __syncthreads();
    for (int off = 1; off < BNODES; off <<= 1) {
        int t2 = (tid < BNODES && tid >= off) ? tmp[tid - off] : 0;
        __syncthreads();
        if (tid < BNODES) tmp[tid] += t2;
        __syncthreads();
    }
    int gbase = bbase[b];
    if (tid < BNODES) {
        int exc = tmp[tid] - pc;           // 4-aligned (scan of mult-of-4)
        lcur[tid] = exc;
        int node = (b << LOCB) + tid;
        if (node < n) {
            cnt[node]  = v;
            offs[node] = gbase + exc;
            inv[node]  = rsqrtf((float)(v + 1));
        }
        for (int j = v; j < pc; ++j)       // pad slots -> zero-source index
            sorted[gbase + exc + j] = n;
    }
    __syncthreads();
    for (int i = tid; i < len4; i += 256) {
        iv4 p4 = b4[i];
        #pragma unroll
        for (int k = 0; k < 4; ++k) {
            unsigned pk = (unsigned)p4[k];
            if ((pk & ROWMASK) < (unsigned)n) {
                int loc = (pk >> ROWBITS) & (BNODES - 1);
                int pos = atomicAdd(&lcur[loc], 1);          // LDS int atomic
                if ((unsigned)pos < (unsigned)(CAP + BSLACK))
                    sorted[gbase + pos] = (int)(pk & ROWMASK);
            }
        }
    }
    for (int i = len4 * 4 + tid; i < len; i += 256) {
        unsigned pk = (unsigned)barr[base + i];
        if ((pk & ROWMASK) < (unsigned)n) {
            int loc = (pk >> ROWBITS) & (BNODES - 1);
            int pos = atomicAdd(&lcur[loc], 1);
            if ((unsigned)pos < (unsigned)(CAP + BSLACK))
                sorted[gbase + pos] = (int)(pk & ROWMASK);
        }
    }
}

// ---------------- linear1: xW1s_bf = bf16((x@W1)*inv), xT1 = x@t1_W + t1_b -
__global__ __launch_bounds__(256) void linear1_kernel(
    const float* __restrict__ x, const float* __restrict__ W1,
    const float* __restrict__ T1, const float* __restrict__ t1b,
    const float* __restrict__ inv,
    unsigned short* __restrict__ xW1s_bf, float* __restrict__ xT1, int n)
{
    __shared__ float Wc[INCH][32];        // [:,0:16]=W1, [:,16:32]=t1_W
    __shared__ float xs[16][INCH + 4];
    int tid = threadIdx.x;

    for (int i = tid; i < INCH * C1; i += 256) {
        int k = i / C1, c = i % C1;
        Wc[k][c]      = W1[i];
        Wc[k][c + 16] = T1[i];
    }
    int node0 = blockIdx.x * 16;
    for (int i = tid; i < 16 * (INCH / 4); i += 256) {
        int r = i / (INCH / 4);
        int cc = i % (INCH / 4);
        int node = node0 + r;
        float4 v = make_float4(0.f, 0.f, 0.f, 0.f);
        if (node < n) v = ((const float4*)x)[(size_t)node * (INCH / 4) + cc];
        ((float4*)&xs[r][0])[cc] = v;
    }
    __syncthreads();

    int ch = tid & 15, nl = tid >> 4;
    int node = node0 + nl;
    if (node >= n) return;
    float a1 = 0.f, a2 = 0.f;
    #pragma unroll
    for (int k = 0; k < INCH; ++k) {
        float xv = xs[nl][k];
        a1 += xv * Wc[k][ch];
        a2 += xv * Wc[k][ch + 16];
    }
    xW1s_bf[(node << 4) + ch] = f2bf(a1 * inv[node]);  // pre-scaled by inv[src]
    xT1[(node << 4) + ch]     = a2 + t1b[ch];
}

// ---- gather core: 4 lanes/node (2 edge-chunk-parities x 2 channel-halves).
//      Lane pr handles 4 CONSECUTIVE edges per 8 (aligned dwordx4 index load
//      + 4 ushort8 gathers), register accumulation, shfl_xor(2) combine.
//      Segments are 4-padded with zero-source index n -> no tail loop.
#define GATHER_ACC(SRCBUF)                                                    \
    float a0 = 0.f, a1 = 0.f, a2 = 0.f, a3 = 0.f,                             \
          a4 = 0.f, a5 = 0.f, a6 = 0.f, a7 = 0.f;                             \
    {                                                                         \
        int p  = beg + (pr << 2);                                             \
        int pe = beg + m;                                                     \
        for (; p + 3 < pe; p += 8) {                                          \
            iv4 s4 = *(const iv4*)(sorted + p);          /* 16B aligned */    \
            usv8 v0 = *(const usv8*)(SRCBUF + ((size_t)(unsigned)s4[0] << 4) + chb); \
            usv8 v1 = *(const usv8*)(SRCBUF + ((size_t)(unsigned)s4[1] << 4) + chb); \
            usv8 v2 = *(const usv8*)(SRCBUF + ((size_t)(unsigned)s4[2] << 4) + chb); \
            usv8 v3 = *(const usv8*)(SRCBUF + ((size_t)(unsigned)s4[3] << 4) + chb); \
            a0 += bf2f(v0[0]) + bf2f(v1[0]) + bf2f(v2[0]) + bf2f(v3[0]);      \
            a1 += bf2f(v0[1]) + bf2f(v1[1]) + bf2f(v2[1]) + bf2f(v3[1]);      \
            a2 += bf2f(v0[2]) + bf2f(v1[2]) + bf2f(v2[2]) + bf2f(v3[2]);      \
            a3 += bf2f(v0[3]) + bf2f(v1[3]) + bf2f(v2[3]) + bf2f(v3[3]);      \
            a4 += bf2f(v0[4]) + bf2f(v1[4]) + bf2f(v2[4]) + bf2f(v3[4]);      \
            a5 += bf2f(v0[5]) + bf2f(v1[5]) + bf2f(v2[5]) + bf2f(v3[5]);      \
            a6 += bf2f(v0[6]) + bf2f(v1[6]) + bf2f(v2[6]) + bf2f(v3[6]);      \
            a7 += bf2f(v0[7]) + bf2f(v1[7]) + bf2f(v2[7]) + bf2f(v3[7]);      \
        }                                                                     \
    }                                                                         \
    a0 += __shfl_xor(a0, 2); a1 += __shfl_xor(a1, 2);                         \
    a2 += __shfl_xor(a2, 2); a3 += __shfl_xor(a3, 2);                         \
    a4 += __shfl_xor(a4, 2); a5 += __shfl_xor(a5, 2);                         \
    a6 += __shfl_xor(a6, 2); a7 += __shfl_xor(a7, 2);

// ---------------- agg1 CSR: register gather + fused epilogue1 --------------
// 64 nodes/block, 256 threads: node = blk*64 + tid/4; lane quad = {parity, chb}
__global__ __launch_bounds__(256) void agg1_csr_kernel(
    const int* __restrict__ sorted, const int* __restrict__ offs,
    const int* __restrict__ cnt, const float* __restrict__ inv,
    const unsigned short* __restrict__ xW1s_bf, const float* __restrict__ xT1,
    const float* __restrict__ b1,
    float* __restrict__ h, unsigned short* __restrict__ hs_bf, int n)
{
    int tid = threadIdx.x;
    int node = blockIdx.x * 64 + (tid >> 2);
    int pr  = (tid >> 1) & 1;        // edge-chunk parity
    int chb = (tid & 1) << 3;        // channel half: 0..7 / 8..15
    int beg = 0, m = 0;
    if (node < n) { beg = offs[node]; m = (cnt[node] + 3) & ~3; }

    GATHER_ACC(xW1s_bf)

    if (node >= n || pr != 0) return;     // quad-uniform wrt shfl partners
    size_t idx = ((size_t)node << 4) + chb;
    usv8 selfv = *(const usv8*)(xW1s_bf + idx);
    float ic = inv[node];
    float hv0 = fmaxf((a0 + bf2f(selfv[0])) * ic + b1[chb + 0], 0.f) + xT1[idx + 0];
    float hv1 = fmaxf((a1 + bf2f(selfv[1])) * ic + b1[chb + 1], 0.f) + xT1[idx + 1];
    float hv2 = fmaxf((a2 + bf2f(selfv[2])) * ic + b1[chb + 2], 0.f) + xT1[idx + 2];
    float hv3 = fmaxf((a3 + bf2f(selfv[3])) * ic + b1[chb + 3], 0.f) + xT1[idx + 3];
    float hv4 = fmaxf((a4 + bf2f(selfv[4])) * ic + b1[chb + 4], 0.f) + xT1[idx + 4];
    float hv5 = fmaxf((a5 + bf2f(selfv[5])) * ic + b1[chb + 5], 0.f) + xT1[idx + 5];
    float hv6 = fmaxf((a6 + bf2f(selfv[6])) * ic + b1[chb + 6], 0.f) + xT1[idx + 6];
    float hv7 = fmaxf((a7 + bf2f(selfv[7])) * ic + b1[chb + 7], 0.f) + xT1[idx + 7];
    ((float4*)(h + idx))[0] = make_float4(hv0, hv1, hv2, hv3);
    ((float4*)(h + idx))[1] = make_float4(hv4, hv5, hv6, hv7);
    usv8 hb;
    hb[0] = f2bf(hv0 * ic); hb[1] = f2bf(hv1 * ic);
    hb[2] = f2bf(hv2 * ic); hb[3] = f2bf(hv3 * ic);
    hb[4] = f2bf(hv4 * ic); hb[5] = f2bf(hv5 * ic);
    hb[6] = f2bf(hv6 * ic); hb[7] = f2bf(hv7 * ic);
    *(usv8*)(hs_bf + idx) = hb;
}

// ---------------- agg2: register gather + fused 16->64 linears -------------
// 64 nodes/block. Gather into regs, plain LDS stores (exclusive), matmul epi.
__global__ __launch_bounds__(256) void agg2_fused_kernel(
    const int* __restrict__ sorted, const int* __restrict__ offs,
    const int* __restrict__ cnt, const float* __restrict__ inv,
    const unsigned short* __restrict__ hs_bf, const float* __restrict__ h,
    const float* __restrict__ W2, const float* __restrict__ T2,
    const float* __restrict__ b2, const float* __restrict__ t2b,
    float* __restrict__ out, int n)
{
    __shared__ float Wc[C1][128];     // [:,0:64]=W2, [:,64:128]=t2_W (8 KB)
    __shared__ float acc_s[64][C1];   // aggregated (incl. self, *ic)   (4 KB)
    __shared__ float h_s[64][C1];     // unscaled h for identity2       (4 KB)
    int tid = threadIdx.x;

    for (int i = tid; i < C1 * 128; i += 256) {
        int k = i >> 7, c = i & 127;
        Wc[k][c] = (c < 64) ? W2[k * C2 + c] : T2[k * C2 + (c - 64)];
    }
    {   // stage h rows (contiguous across the block -> coalesced float4)
        int node0 = blockIdx.x * 64;
        if (tid < 256) {
            float4 v = make_float4(0.f, 0.f, 0.f, 0.f);
            if (node0 + (tid >> 2) < n)
                v = ((const float4*)h)[(size_t)node0 * 4 + tid];
            ((float4*)&h_s[0][0])[tid] = v;
        }
    }

    int node = blockIdx.x * 64 + (tid >> 2);
    int pr  = (tid >> 1) & 1;
    int chb = (tid & 1) << 3;
    int beg = 0, m = 0;
    if (node < n) { beg = offs[node]; m = (cnt[node] + 3) & ~3; }

    GATHER_ACC(hs_bf)

    if (node < n && pr == 0) {
        size_t idx = ((size_t)node << 4) + chb;
        usv8 selfv = *(const usv8*)(hs_bf + idx);
        float ic = inv[node];
        int loc = tid >> 2;
        float4* ap = (float4*)&acc_s[loc][chb];
        ap[0] = make_float4((a0 + bf2f(selfv[0])) * ic, (a1 + bf2f(selfv[1])) * ic,
                            (a2 + bf2f(selfv[2])) * ic, (a3 + bf2f(selfv[3])) * ic);
        ap[1] = make_float4((a4 + bf2f(selfv[4])) * ic, (a5 + bf2f(selfv[5])) * ic,
                            (a6 + bf2f(selfv[6])) * ic, (a7 + bf2f(selfv[7])) * ic);
    }
    __syncthreads();

    // 16->64 matmuls: weights hoisted to registers, acc/h_s broadcast reads
    int och = tid & 63, g = tid >> 6;        // wave g handles locs [16g, 16g+16)
    float w1r[C1], w2r[C1];
    #pragma unroll
    for (int k = 0; k < C1; ++k) { w1r[k] = Wc[k][och]; w2r[k] = Wc[k][och + 64]; }
    float bb = b2[och], tb = t2b[och];
    for (int q = 0; q < 16; ++q) {
        int loc = (g << 4) + q;
        int node2 = blockIdx.x * 64 + loc;
        if (node2 >= n) continue;
        float s1 = bb, s2 = tb;
        #pragma unroll
        for (int k = 0; k < C1; ++k) {
            s1 += acc_s[loc][k] * w1r[k];
            s2 += h_s[loc][k]   * w2r[k];
        }
        out[(size_t)node2 * C2 + och] = fmaxf(s1, 0.f) + s2;
    }
}

extern "C" void kernel_launch(void* const* d_in, const int* in_sizes, int n_in,
                              void* d_out, int out_size, void* d_ws, size_t ws_size,
                              hipStream_t stream) {
    const float* x   = (const float*)d_in[0];
    const int*   ei  = (const int*)d_in[1];
    const float* W1  = (const float*)d_in[2];
    const float* b1  = (const float*)d_in[3];
    const float* W2  = (const float*)d_in[4];
    const float* b2  = (const float*)d_in[5];
    const float* T1  = (const float*)d_in[6];
    const float* t1b = (const float*)d_in[7];
    const float* T2  = (const float*)d_in[8];
    const float* t2b = (const float*)d_in[9];
    float* out = (float*)d_out;

    const int n = in_sizes[0] / INCH;       // 100000
    const int e = in_sizes[1] / 2;          // 3200000
    const int* row = ei;
    const int* col = ei + e;
    const int K = (n + BNODES - 1) >> LOCB; // 782 buckets

    // workspace layout — data-indexed buffers (sorted, barr) last
    char* ws = (char*)d_ws;
    int*   gcur  = (int*)ws;                          ws += 4096;
    int*   bbase = (int*)ws;                          ws += 4096;
    int*   cnt   = (int*)ws;                          ws += (size_t)n * 4;
    int*   offs  = (int*)ws;                          ws += (size_t)n * 4;
    float* inv   = (float*)ws;                        ws += (size_t)n * 4;
    float* xT1   = (float*)ws;                        ws += (size_t)n * C1 * 4;
    float* h     = (float*)ws;                        ws += (size_t)n * C1 * 4;
    unsigned short* xW1s_bf = (unsigned short*)ws;    ws += (size_t)n * C1 * 2 + 64; // +zero row n
    unsigned short* hs_bf   = (unsigned short*)ws;    ws += (size_t)n * C1 * 2 + 64; // +zero row n
    int*   sorted= (int*)ws;                          ws += ((size_t)K * CAP + (size_t)K * BSLACK) * 4;
    int*   barr  = (int*)ws;                          ws += (size_t)K * CAP * 4;

    const int B = 256;
    const int nbb = 390;     // bucket_kernel blocks

    binit_kernel      <<<(K + B - 1) / B, B, 0, stream>>>(gcur, K,
                        (int*)(xW1s_bf + (size_t)n * C1), (int*)(hs_bf + (size_t)n * C1));
    bucket_kernel     <<<nbb, B, 0, stream>>>(row, col, gcur, barr, e, n, K, nbb);
    bucket_scan_kernel<<<1, 1024, 0, stream>>>(gcur, bbase, K);
    sort_kernel       <<<K, B, 0, stream>>>(barr, gcur, bbase, cnt, offs, inv, sorted, n);

    linear1_kernel <<<(n + 15) / 16, B, 0, stream>>>(x, W1, T1, t1b, inv, xW1s_bf, xT1, n);
    agg1_csr_kernel<<<(n + 63) / 64, B, 0, stream>>>(sorted, offs, cnt, inv, xW1s_bf, xT1, b1, h, hs_bf, n);

    agg2_fused_kernel<<<(n + 63) / 64, B, 0, stream>>>(sorted, offs, cnt, inv, hs_bf, h,
                                                       W2, T2, b2, t2b, out, n);
}